// Round 1
// 462.929 us; speedup vs baseline: 1.1129x; 1.1129x over previous
//
#include <hip/hip_runtime.h>

// BlockLinear: 64 independent GEMMs [4096x256] @ [256x256]^T + bias, fp32 in/out.
// Cast to bf16 on the fly, MFMA 16x16x32_bf16, fp32 accumulate.
// Memory-bound: ideal ~554 MB @ ~6 TB/s ~= 90 us.
//
// This version: BK=32, double-buffered LDS (48 KB), ONE raw s_barrier per
// K-step (no vmcnt drain -> global prefetch stays in flight), loads issued
// one step ahead, XOR-swizzled LDS (conflict-free reads AND writes).

#define BATCH   4096
#define NBLK    64
#define KB_     256      // in_block (K)
#define OB_     256      // out_block (N)
#define BM      128      // M-tile
#define BK      32       // K-step (one MFMA K per step)
#define SROW    32       // bf16 per LDS row == BK
#define NTHREADS 512     // 8 waves: 2 (M) x 4 (N), each wave 64x64

typedef __attribute__((ext_vector_type(8))) short bf16x8;   // 8 bf16 = 4 VGPRs
typedef __attribute__((ext_vector_type(4))) float f32x4;

__device__ __forceinline__ unsigned short f2bf(float f) {
    unsigned int u = __float_as_uint(f);
    u += 0x7FFFu + ((u >> 16) & 1u);   // round-to-nearest-even
    return (unsigned short)(u >> 16);
}

__device__ __forceinline__ ushort4 cvt4(float4 v) {
    ushort4 b;
    b.x = f2bf(v.x); b.y = f2bf(v.y); b.z = f2bf(v.z); b.w = f2bf(v.w);
    return b;
}

__global__ __launch_bounds__(NTHREADS, 4)   // 4 waves/EU => 2 WGs/CU => regs <= 128
void blocklinear_kernel(const float* __restrict__ x,
                        const float* __restrict__ w,
                        const float* __restrict__ bias,
                        float* __restrict__ out)
{
    // wg%64 = block index -> all m-tiles of one block land on the same XCD
    // (round-robin i%8), keeping that block's weight slice L2-resident.
    const int wg  = blockIdx.x;
    const int blk = wg & 63;
    const int mt  = wg >> 6;          // 0..31
    const int m0  = mt * BM;

    const int tid  = threadIdx.x;
    const int lane = tid & 63;
    const int wave = tid >> 6;        // 0..7
    const int wm   = wave >> 2;       // 0..1  (M)
    const int wn   = wave & 3;        // 0..3  (N)

    __shared__ unsigned short Asm[2][BM  * SROW];   // 2 x 8 KB
    __shared__ unsigned short Bsm[2][OB_ * SROW];   // 2 x 16 KB  -> 48 KB total

    f32x4 acc[4][4] = {};             // 64 fp32 accumulators / lane (AGPR side)

    // ---- staging addresses: 8 threads per row, 128 B contiguous per 8 lanes ----
    const int tr = tid >> 3;              // 0..63
    const int tc = (tid & 7) << 2;        // float col within BK: 0,4,...,28
    const float* pa = x + (size_t)(m0 + tr) * (NBLK * KB_) + (size_t)blk * KB_ + tc;
    const float* pw = w + (size_t)blk * (OB_ * KB_) + (size_t)tr * KB_ + tc;

    // XOR swizzle: permute 16B chunks within each 64B row by (row&3).
    // Write side (ushort units): col ^ ((tr&3)<<3); (row+64k)&3 == row&3, so
    // one offset serves all row strides.
    const int wAB = tr * SROW + (tc ^ ((tr & 3) << 3));

    // ---- frag read offsets (ushort units), same swizzle on the read side ----
    const int lrow = lane & 15;
    const int quad = lane >> 4;
    const int rswz = (quad << 3) ^ ((lrow & 3) << 3);
    const int rA = (wm * 64 + lrow) * SROW + rswz;   // + fm*16*SROW
    const int rB = (wn * 64 + lrow) * SROW + rswz;   // + fn*16*SROW

    float4 ra0, ra1, rb0, rb1, rb2, rb3;   // 6 float4 = 24 VGPRs in flight

#define LOADS(kb_) do {                                                   \
    ra0 = *(const float4*)(pa + (kb_));                                   \
    ra1 = *(const float4*)(pa + (size_t)64 * (NBLK * KB_) + (kb_));       \
    rb0 = *(const float4*)(pw + (kb_));                                   \
    rb1 = *(const float4*)(pw +  64 * KB_ + (kb_));                       \
    rb2 = *(const float4*)(pw + 128 * KB_ + (kb_));                       \
    rb3 = *(const float4*)(pw + 192 * KB_ + (kb_));                       \
} while (0)

#define STAGE(bufi) do {                                                  \
    unsigned short* As_ = Asm[bufi];                                      \
    unsigned short* Bs_ = Bsm[bufi];                                      \
    *(ushort4*)(&As_[wAB])              = cvt4(ra0);                      \
    *(ushort4*)(&As_[wAB +  64 * SROW]) = cvt4(ra1);                      \
    *(ushort4*)(&Bs_[wAB])              = cvt4(rb0);                      \
    *(ushort4*)(&Bs_[wAB +  64 * SROW]) = cvt4(rb1);                      \
    *(ushort4*)(&Bs_[wAB + 128 * SROW]) = cvt4(rb2);                      \
    *(ushort4*)(&Bs_[wAB + 192 * SROW]) = cvt4(rb3);                      \
} while (0)

    // ---- prologue: fill buf0, issue step-1 loads ----
    LOADS(0);
    STAGE(0);
    LOADS(BK);
    asm volatile("s_waitcnt lgkmcnt(0)" ::: "memory");
    __builtin_amdgcn_s_barrier();

    // ---- main loop: one barrier per K-step, global loads 1.5 steps ahead ----
    for (int s = 0; s < 8; ++s) {
        const int cur = s & 1;

        if (s < 7) STAGE(cur ^ 1);           // cvt+write data for step s+1
        if (s < 6) LOADS((s + 2) * BK);      // issue loads for step s+2 (no wait)

        const unsigned short* As_ = Asm[cur];
        const unsigned short* Bs_ = Bsm[cur];

        bf16x8 bfr[4];
        #pragma unroll
        for (int fn = 0; fn < 4; fn++)
            bfr[fn] = *(const bf16x8*)(&Bs_[rB + fn * 16 * SROW]);
        #pragma unroll
        for (int fm = 0; fm < 4; fm++) {
            bf16x8 af = *(const bf16x8*)(&As_[rA + fm * 16 * SROW]);
            #pragma unroll
            for (int fn = 0; fn < 4; fn++)
                acc[fm][fn] = __builtin_amdgcn_mfma_f32_16x16x32_bf16(
                    af, bfr[fn], acc[fm][fn], 0, 0, 0);
        }

        // Producer/consumer handoff needs only LDS drained; plain global->reg
        // loads stay in flight across the raw barrier (no vmcnt(0) drain).
        asm volatile("s_waitcnt lgkmcnt(0)" ::: "memory");
        __builtin_amdgcn_s_barrier();
    }

    // ---- epilogue: C/D layout col=lane&15, row=quad*4+reg ----
    #pragma unroll
    for (int fn = 0; fn < 4; fn++) {
        int col = wn * 64 + fn * 16 + lrow;
        float bv = bias[blk * OB_ + col];
        #pragma unroll
        for (int fm = 0; fm < 4; fm++) {
            #pragma unroll
            for (int r = 0; r < 4; r++) {
                int row = m0 + wm * 64 + fm * 16 + quad * 4 + r;
                out[(size_t)row * (NBLK * OB_) + blk * OB_ + col] = acc[fm][fn][r] + bv;
            }
        }
    }
}

extern "C" void kernel_launch(void* const* d_in, const int* in_sizes, int n_in,
                              void* d_out, int out_size, void* d_ws, size_t ws_size,
                              hipStream_t stream) {
    const float* x    = (const float*)d_in[0];
    const float* w    = (const float*)d_in[1];
    const float* bias = (const float*)d_in[2];
    float* out        = (float*)d_out;

    dim3 grid((BATCH / BM) * NBLK);   // 32 * 64 = 2048 WGs
    dim3 block(NTHREADS);
    blocklinear_kernel<<<grid, block, 0, stream>>>(x, w, bias, out);
}